// Round 10
// baseline (197.794 us; speedup 1.0000x reference)
//
#include <hip/hip_runtime.h>

#define LDIM 4096
#define DDIM 64
#define KCODES 1024
#define BDIM 16
#define NROWS 65536   // BDIM * LDIM
#define NSLICE 8
#define SLICE_ROWS (NROWS / NSLICE)   // 8192

typedef __attribute__((ext_vector_type(8))) short short8;
typedef __attribute__((ext_vector_type(16))) float float16v;

__device__ __forceinline__ unsigned int orderf(float f) {
  unsigned int u = __float_as_uint(f);
  return (u & 0x80000000u) ? ~u : (u | 0x80000000u);
}

__device__ __forceinline__ unsigned long long shfl_xor_u64(unsigned long long v, int m) {
  int lo = __shfl_xor((int)(unsigned int)(v & 0xffffffffull), m, 64);
  int hi = __shfl_xor((int)(unsigned int)(v >> 32), m, 64);
  return ((unsigned long long)(unsigned int)hi << 32) | (unsigned int)lo;
}

// bf16 RNE high part (as ushort bits)
__device__ __forceinline__ unsigned int bf16_rne(float x) {
  unsigned int u = __float_as_uint(x);
  return (u + 0x7FFFu + ((u >> 16) & 1u)) >> 16;
}

// async global->LDS, 16 B per lane; lds dest = wave-uniform base + lane*16
__device__ __forceinline__ void gl_lds16(const void* g, void* l) {
  __builtin_amdgcn_global_load_lds(
      (const __attribute__((address_space(1))) void*)g,
      (__attribute__((address_space(3))) void*)l, 16, 0, 0);
}

// ---------------------------------------------------------------------------
// prep: per-code norm + softmax table + FRAGMENT-LOAD-ORDER bf16 codebook.
// For tile t (32 codes), frag q (0..3 hi s, 4..7 lo s), lane (h*32+m):
// 8 shorts = B-frag of code c=t*32+m, dims d=16s+8h+[0,8). Short index:
// t*4096 + q*512 + (h*32+m)*8 + j -> 1 KB contiguous per wave load/DMA.
// ---------------------------------------------------------------------------
__global__ void prep_kernel(const float* __restrict__ Ew,
                            float* __restrict__ enorm,
                            float* __restrict__ SE,
                            unsigned short* __restrict__ Epk2) {
  int k = blockIdx.x;
  int d = threadIdx.x;
  float v = Ew[k * DDIM + d];
  float n2 = v * v;
  #pragma unroll
  for (int o = 32; o > 0; o >>= 1) n2 += __shfl_xor(n2, o, 64);
  float m = v;
  #pragma unroll
  for (int o = 32; o > 0; o >>= 1) m = fmaxf(m, __shfl_xor(m, o, 64));
  float e = expf(v - m);
  float Z = e;
  #pragma unroll
  for (int o = 32; o > 0; o >>= 1) Z += __shfl_xor(Z, o, 64);
  SE[k * DDIM + d] = e / Z;
  if (d == 0) enorm[k] = n2;

  unsigned int rh = bf16_rne(v);
  float hif = __uint_as_float(rh << 16);
  unsigned int rl = bf16_rne(v - hif);
  int tile = k >> 5, mm = k & 31;
  int s = d >> 4, h = (d >> 3) & 1, j = d & 7;
  int base = tile * 4096 + (h * 32 + mm) * 8 + j;
  Epk2[base + s * 512]        = (unsigned short)rh;
  Epk2[base + (4 + s) * 512]  = (unsigned short)rl;
}

// ---------------------------------------------------------------------------
// FUSED argmin + quantize + KL, with a hipBLASLt-style pipelined K-loop:
// B staged block-cooperatively into 2 LDS slots via global_load_lds; per
// chunk: s_waitcnt vmcnt(0) (only current chunk in flight) -> BARE s_barrier
// (no compiler drain) -> issue next chunk's DMA -> compute 4 tiles. The
// prefetch overlaps compute and is never drained by a barrier. B bytes per
// CU drop 4x vs per-wave L2 streaming (one stage per block, 4 waves share).
// Race-safe: slot parity i&1; chunk i+1's DMA (after barrier i) only
// overwrites the slot whose readers all passed barrier i.
// ---------------------------------------------------------------------------
__launch_bounds__(256, 2)
__global__ void argmin_fused_kernel(const float* __restrict__ inp,
                                    const unsigned short* __restrict__ Epk2,
                                    const float* __restrict__ enorm,
                                    const float* __restrict__ Ew,
                                    const float* __restrict__ SE,
                                    int* __restrict__ idx_ws,
                                    float* __restrict__ outidx,
                                    float* __restrict__ out,
                                    float* __restrict__ klacc) {
  __shared__ unsigned short slots[2][16384];   // 2 x 32 KB (128 codes each)
  __shared__ float ens[KCODES];                // 4 KB
  __shared__ int kbuf[4][32];

  const int tid = threadIdx.x;
  const int lane = tid & 63;
  const int w = tid >> 6;
  const int half = lane >> 5;
  const int m = lane & 31;
  const int row_base = blockIdx.x * 128 + w * 32;
  const int b = row_base >> 12;
  const int l0 = row_base & 4095;
  const float* xp = inp + (size_t)b * DDIM * LDIM + l0 + m;
  float* op = out + (size_t)b * DDIM * LDIM + l0 + m;

  // ---- DMA chunk 0 into slot 0 (overlaps x staging below) --------------
  {
    const char* src = (const char*)Epk2 + w * 8192 + (lane << 4);
    char* dst = (char*)&slots[0][0] + w * 8192;
    #pragma unroll
    for (int q = 0; q < 8; q++)
      gl_lds16(src + q * 1024, dst + q * 1024);
  }
  // ---- stage enorm into LDS -------------------------------------------
  {
    float4 v = ((const float4*)enorm)[tid];
    *(float4*)&ens[tid << 2] = v;
  }

  // ---- x once: fp32 regs + bf16 hi/lo A-frags --------------------------
  // lane (m,h) holds row m, dims d = 16s + 8h + j  (s=0..3, j=0..7)
  float xr[32];
  short8 afr[8];   // 0..3 = hi frags, 4..7 = lo frags
  #pragma unroll
  for (int s = 0; s < 4; s++) {
    #pragma unroll
    for (int j = 0; j < 8; j++) {
      int d = 16 * s + 8 * half + j;
      float x = xp[(size_t)d * LDIM];
      xr[s * 8 + j] = x;
      unsigned int rh = bf16_rne(x);
      float hif = __uint_as_float(rh << 16);
      unsigned int rl = bf16_rne(x - hif);
      afr[s][j] = (short)(unsigned short)rh;
      afr[4 + s][j] = (short)(unsigned short)rl;
    }
  }
  __syncthreads();   // drains chunk-0 DMA + ens stores; the only full barrier

  float bsc[16];
  int bix[16];
  #pragma unroll
  for (int j = 0; j < 16; j++) { bsc[j] = 1e30f; bix[j] = 0; }

  #pragma unroll 1
  for (int i = 0; i < 8; i++) {
    // current chunk's DMA (issued last iteration) must be complete...
    asm volatile("s_waitcnt vmcnt(0)" ::: "memory");
    // ...in ALL waves. Bare barrier: no compiler-inserted memory drain.
    __builtin_amdgcn_s_barrier();
    // prefetch chunk i+1 -> opposite slot; stays in flight through compute
    if (i < 7) {
      const char* src = (const char*)Epk2 + (i + 1) * 32768 + w * 8192 + (lane << 4);
      char* dst = (char*)&slots[(i + 1) & 1][0] + w * 8192;
      #pragma unroll
      for (int q = 0; q < 8; q++)
        gl_lds16(src + q * 1024, dst + q * 1024);
    }
    const unsigned short* cur = &slots[i & 1][0];

    #pragma unroll
    for (int tile = 0; tile < 4; tile++) {
      const int gt = i * 4 + tile;
      const int ci = gt * 32 + m;
      const float en = ens[ci];
      const unsigned short* tb = cur + tile * 4096 + lane * 8;

      short8 bfr[8];
      #pragma unroll
      for (int s = 0; s < 4; s++) {
        bfr[s]     = *(const short8*)(tb + s * 512);
        bfr[4 + s] = *(const short8*)(tb + 2048 + s * 512);
      }

      float16v a0 = {}, a1 = {}, a2 = {};
      #pragma unroll
      for (int s = 0; s < 4; s++) {
        a0 = __builtin_amdgcn_mfma_f32_32x32x16_bf16(afr[s], bfr[s], a0, 0, 0, 0);
        a1 = __builtin_amdgcn_mfma_f32_32x32x16_bf16(afr[s], bfr[4 + s], a1, 0, 0, 0);
        a2 = __builtin_amdgcn_mfma_f32_32x32x16_bf16(afr[4 + s], bfr[s], a2, 0, 0, 0);
      }
      #pragma unroll
      for (int j = 0; j < 16; j++) {
        float sc = fmaf(-2.f, a0[j] + a1[j] + a2[j], en);
        if (sc < bsc[j]) { bsc[j] = sc; bix[j] = ci; }  // ascending ci: ties -> smaller
      }
    }
  }

  // C layout: row = (j&3)+8*(j>>2)+4*half, col = m. Butterfly min over cols.
  #pragma unroll
  for (int j = 0; j < 16; j++) {
    unsigned long long key =
        ((unsigned long long)orderf(bsc[j]) << 32) | (unsigned int)bix[j];
    #pragma unroll
    for (int mm = 1; mm < 32; mm <<= 1) {
      unsigned long long o = shfl_xor_u64(key, mm);
      if (o < key) key = o;
    }
    if (m == 0) {
      int row_local = (j & 3) + 8 * (j >> 2) + 4 * half;
      int grow = row_base + row_local;
      int cidx = (int)(key & 0xffffffffull);
      idx_ws[grow] = cidx;
      outidx[grow] = (float)cidx;
      kbuf[w][row_local] = cidx;
    }
  }

  // wave-synchronous LDS round-trip (same wave wrote it; no barrier needed)
  const int km = kbuf[w][m];

  // ---- epilogue: quantized out + KL, from registers + L2 gathers -------
  const float* SEk = SE + km * DDIM + 8 * half;
  const float* Ewk = Ew + km * DDIM + 8 * half;
  float Zh = 0.f, S1h = 0.f, Uh = 0.f;
  #pragma unroll
  for (int s = 0; s < 4; s++) {
    float qv[8], ev[8];
    *(float4*)&qv[0] = *(const float4*)(SEk + 16 * s);
    *(float4*)&qv[4] = *(const float4*)(SEk + 16 * s + 4);
    *(float4*)&ev[0] = *(const float4*)(Ewk + 16 * s);
    *(float4*)&ev[4] = *(const float4*)(Ewk + 16 * s + 4);
    #pragma unroll
    for (int j = 0; j < 8; j++) {
      float x = xr[s * 8 + j];
      float e = expf(x);
      Zh += e;
      S1h += e * x;
      Uh += e * qv[j];
      op[(size_t)(16 * s + 8 * half + j) * LDIM] = ev[j];
    }
  }
  float Zt = Zh + __shfl_xor(Zh, 32, 64);
  float S1t = S1h + __shfl_xor(S1h, 32, 64);
  float Ut = Uh + __shfl_xor(Uh, 32, 64);
  float kl = (half == 0) ? ((S1t - Ut) / Zt - logf(Zt)) : 0.f;
  #pragma unroll
  for (int o = 32; o > 0; o >>= 1) kl += __shfl_xor(kl, o, 64);
  if (lane == 0) atomicAdd(klacc, kl);
}

// ---------------------------------------------------------------------------
// dw partial: dimension-sliced histogram, 512 thr/block; d==0 blocks also
// histogram counts. Zero global atomics.
// ---------------------------------------------------------------------------
__launch_bounds__(512)
__global__ void dw_partial_kernel(const float* __restrict__ inp,
                                  const int* __restrict__ idx_ws,
                                  float* __restrict__ partial,
                                  float* __restrict__ pcounts) {
  __shared__ float dwp[KCODES];
  __shared__ float cnt[KCODES];
  const int d = blockIdx.x & 63;
  const int slice = blockIdx.x >> 6;
  const int tid = threadIdx.x;
  const bool do_cnt = (d == 0);

  #pragma unroll
  for (int i = 0; i < KCODES / 512; i++) {
    dwp[tid + i * 512] = 0.f;
    cnt[tid + i * 512] = 0.f;
  }
  __syncthreads();

  const int r0 = slice * SLICE_ROWS;
  for (int i = tid; i < SLICE_ROWS; i += 512) {
    int r = r0 + i;
    int b = r >> 12, l = r & 4095;
    float x = inp[(size_t)b * DDIM * LDIM + (size_t)d * LDIM + l];
    int k = idx_ws[r];
    atomicAdd(&dwp[k], x);
    if (do_cnt) atomicAdd(&cnt[k], 1.0f);
  }
  __syncthreads();

  float* dst = partial + ((size_t)slice * 64 + d) * KCODES;
  #pragma unroll
  for (int i = 0; i < KCODES / 512; i++) dst[tid + i * 512] = dwp[tid + i * 512];
  if (do_cnt) {
    float* cd = pcounts + (size_t)slice * KCODES;
    #pragma unroll
    for (int i = 0; i < KCODES / 512; i++) cd[tid + i * 512] = cnt[tid + i * 512];
  }
}

// ---------------------------------------------------------------------------
// csp + perplexity (from count partials). 1 block x 1024.
// ---------------------------------------------------------------------------
__global__ void csp_kernel(const float* __restrict__ ema_cs,
                           const float* __restrict__ pcounts,
                           float* __restrict__ csp,
                           float* __restrict__ perp_out) {
  __shared__ float red1[16], red2[16];
  int k = threadIdx.x;
  float c = 0.f;
  #pragma unroll
  for (int sl = 0; sl < NSLICE; sl++) c += pcounts[sl * KCODES + k];
  float cs = ema_cs[k] * 0.9f + 0.1f * c;
  float n = cs;
  #pragma unroll
  for (int o = 32; o > 0; o >>= 1) n += __shfl_xor(n, o, 64);
  if ((k & 63) == 0) red1[k >> 6] = n;
  float a = c * (1.0f / 65536.0f);
  float ent = a * logf(a + 1e-10f);
  float es = ent;
  #pragma unroll
  for (int o = 32; o > 0; o >>= 1) es += __shfl_xor(es, o, 64);
  if ((k & 63) == 0) red2[k >> 6] = es;
  __syncthreads();
  if (k == 0) {
    float t1 = 0.f, t2 = 0.f;
    for (int i = 0; i < 16; i++) { t1 += red1[i]; t2 += red2[i]; }
    red1[0] = t1;
    *perp_out = expf(-t2);
  }
  __syncthreads();
  float N = red1[0];
  csp[k] = (cs + 1e-5f) / (N + 1024.0f * 1e-5f) * N;
}

// ---------------------------------------------------------------------------
// reduce partials + embed epilogue + loss scalar.
// ---------------------------------------------------------------------------
__launch_bounds__(256)
__global__ void reduce_embed_kernel(const float* __restrict__ partial,
                                    const float* __restrict__ emaw,
                                    const float* __restrict__ csp,
                                    const float* __restrict__ klacc,
                                    float* __restrict__ emb_out,
                                    float* __restrict__ loss_out) {
  int i = blockIdx.x * 256 + threadIdx.x;
  int k = i >> 6, d = i & 63;
  float s = 0.f;
  #pragma unroll
  for (int sl = 0; sl < NSLICE; sl++)
    s += partial[((size_t)sl * 64 + d) * KCODES + k];
  float v = fmaf(0.1f, s, emaw[i] * 0.9f);
  emb_out[i] = v / csp[k];
  if (i == 0) *loss_out = 0.1f * (*klacc) * (1.0f / 16.0f);
}

extern "C" void kernel_launch(void* const* d_in, const int* in_sizes, int n_in,
                              void* d_out, int out_size, void* d_ws, size_t ws_size,
                              hipStream_t stream) {
  const float* inp   = (const float*)d_in[0];   // (16,64,4096)
  const float* Ew    = (const float*)d_in[1];   // (1024,64)
  const float* emacs = (const float*)d_in[2];   // (1024,)
  const float* emaw  = (const float*)d_in[3];   // (1024,64)

  float* out      = (float*)d_out;              // (16,64,4096) = 4194304
  float* loss_out = out + 4194304;
  float* perp_out = out + 4194305;
  float* emb_out  = out + 4194306;              // 65536
  float* idxf_out = out + 4194306 + 65536;      // 65536 (indices as float)

  char* ws = (char*)d_ws;
  int*   idx_ws  = (int*)(ws);                  // 262144 B
  float* klacc   = (float*)(ws + 262144);       // 256 B (zeroed)
  float* enorm   = (float*)(ws + 266496);       // 4096 B
  float* csp     = (float*)(ws + 270592);       // 4096 B
  float* SE      = (float*)(ws + 274688);       // 262144 B -> ends 536832
  unsigned short* Epk2 = (unsigned short*)(ws + 536832);  // 262144 B
  // dw partials alias Epk2 (dead after argmin_fused)
  float* partial = (float*)(ws + 536832);       // 2097152 B -> ends 2633984
  float* pcounts = (float*)(ws + 2633984);      // 32768 B  -> ends 2666752

  hipMemsetAsync(ws + 262144, 0, 256, stream);

  prep_kernel<<<KCODES, 64, 0, stream>>>(Ew, enorm, SE, Epk2);
  argmin_fused_kernel<<<512, 256, 0, stream>>>(inp, Epk2, enorm, Ew, SE,
                                               idx_ws, idxf_out, out, klacc);
  dw_partial_kernel<<<64 * NSLICE, 512, 0, stream>>>(inp, idx_ws, partial, pcounts);
  csp_kernel<<<1, 1024, 0, stream>>>(emacs, pcounts, csp, perp_out);
  reduce_embed_kernel<<<NROWS / 256, 256, 0, stream>>>(partial, emaw, csp, klacc,
                                                       emb_out, loss_out);
}

// Round 11
// 178.811 us; speedup vs baseline: 1.1062x; 1.1062x over previous
//
#include <hip/hip_runtime.h>

#define LDIM 4096
#define DDIM 64
#define KCODES 1024
#define BDIM 16
#define NROWS 65536   // BDIM * LDIM
#define NSLICE 8
#define SLICE_ROWS (NROWS / NSLICE)   // 8192

typedef __attribute__((ext_vector_type(8))) short short8;
typedef __attribute__((ext_vector_type(16))) float float16v;

__device__ __forceinline__ unsigned int orderf(float f) {
  unsigned int u = __float_as_uint(f);
  return (u & 0x80000000u) ? ~u : (u | 0x80000000u);
}

__device__ __forceinline__ unsigned long long shfl_xor_u64(unsigned long long v, int m) {
  int lo = __shfl_xor((int)(unsigned int)(v & 0xffffffffull), m, 64);
  int hi = __shfl_xor((int)(unsigned int)(v >> 32), m, 64);
  return ((unsigned long long)(unsigned int)hi << 32) | (unsigned int)lo;
}

// bf16 RNE high part (as ushort bits)
__device__ __forceinline__ unsigned int bf16_rne(float x) {
  unsigned int u = __float_as_uint(x);
  return (u + 0x7FFFu + ((u >> 16) & 1u)) >> 16;
}

// ---------------------------------------------------------------------------
// prep: per-code norm + softmax table + FRAGMENT-LOAD-ORDER bf16 codebook.
// For tile t (32 codes), load-instruction q (0..3 hi s, 4..7 lo s), lane
// (h*32+m): 8 shorts = B-frag of code c=t*32+m, dims d=16s+8h+[0,8).
// Short index: t*4096 + q*512 + (h*32+m)*8 + j -> wave loads are contiguous
// 1 KB, fully coalesced, sequential through the 256 KB table.
// ---------------------------------------------------------------------------
__global__ void prep_kernel(const float* __restrict__ Ew,
                            float* __restrict__ enorm,
                            float* __restrict__ SE,
                            unsigned short* __restrict__ Epk2) {
  int k = blockIdx.x;
  int d = threadIdx.x;
  float v = Ew[k * DDIM + d];
  float n2 = v * v;
  #pragma unroll
  for (int o = 32; o > 0; o >>= 1) n2 += __shfl_xor(n2, o, 64);
  float m = v;
  #pragma unroll
  for (int o = 32; o > 0; o >>= 1) m = fmaxf(m, __shfl_xor(m, o, 64));
  float e = __expf(v - m);
  float Z = e;
  #pragma unroll
  for (int o = 32; o > 0; o >>= 1) Z += __shfl_xor(Z, o, 64);
  SE[k * DDIM + d] = e / Z;
  if (d == 0) enorm[k] = n2;

  unsigned int rh = bf16_rne(v);
  float hif = __uint_as_float(rh << 16);
  unsigned int rl = bf16_rne(v - hif);
  int tile = k >> 5, mm = k & 31;
  int s = d >> 4, h = (d >> 3) & 1, j = d & 7;
  int base = tile * 4096 + (h * 32 + mm) * 8 + j;
  Epk2[base + s * 512]        = (unsigned short)rh;
  Epk2[base + (4 + s) * 512]  = (unsigned short)rl;
}

// ---------------------------------------------------------------------------
// argmin: LDS-free, barrier-free, atomic-free (the R8 structure — fastest
// measured). One wave owns 32 rows; B streamed from the fragment-linear
// codebook (contiguous 1 KB wave loads, sequential, L1/L2-hot); register
// double-buffered tiles; 3 independent MFMA chains; butterfly argmin.
// score = ||E||^2 - 2 x.E  (row-constant ||x||^2 dropped; order/ties kept).
// ---------------------------------------------------------------------------
__launch_bounds__(256, 2)
__global__ void argmin_kernel(const float* __restrict__ inp,
                              const unsigned short* __restrict__ Epk2,
                              const float* __restrict__ enorm,
                              int* __restrict__ idx_ws,
                              float* __restrict__ outidx) {
  const int tid = threadIdx.x;
  const int lane = tid & 63;
  const int w = tid >> 6;
  const int half = lane >> 5;
  const int m = lane & 31;
  const int row_base = blockIdx.x * 128 + w * 32;
  const int b = row_base >> 12;
  const int l0 = row_base & 4095;
  const float* xp = inp + (size_t)b * DDIM * LDIM + l0 + m;

  // ---- A-frags from global: lane holds x[row=m][d=16s+8*half+j] --------
  short8 afr[8];   // 0..3 = hi frags, 4..7 = lo frags
  #pragma unroll
  for (int s = 0; s < 4; s++) {
    #pragma unroll
    for (int j = 0; j < 8; j++) {
      int d = 16 * s + 8 * half + j;
      float x = xp[(size_t)d * LDIM];
      unsigned int rh = bf16_rne(x);
      float hif = __uint_as_float(rh << 16);
      unsigned int rl = bf16_rne(x - hif);
      afr[s][j] = (short)(unsigned short)rh;
      afr[4 + s][j] = (short)(unsigned short)rl;
    }
  }

  float bsc[16];
  int bix[16];
  #pragma unroll
  for (int j = 0; j < 16; j++) { bsc[j] = 1e30f; bix[j] = 0; }

  const unsigned short* eb = Epk2 + lane * 8;

  short8 bA[8], bB[8];
  float enA, enB;

  #pragma unroll
  for (int s = 0; s < 4; s++) {
    bA[s]     = *(const short8*)(eb + s * 512);
    bA[4 + s] = *(const short8*)(eb + 2048 + s * 512);
  }
  enA = enorm[m];

  #pragma unroll 1
  for (int i = 0; i < 16; i++) {
    const int tB = 2 * i + 1;
    {
      const unsigned short* p = eb + tB * 4096;
      #pragma unroll
      for (int s = 0; s < 4; s++) {
        bB[s]     = *(const short8*)(p + s * 512);
        bB[4 + s] = *(const short8*)(p + 2048 + s * 512);
      }
      enB = enorm[tB * 32 + m];
    }
    {
      float16v a0 = {}, a1 = {}, a2 = {};
      #pragma unroll
      for (int s = 0; s < 4; s++) {
        a0 = __builtin_amdgcn_mfma_f32_32x32x16_bf16(afr[s], bA[s], a0, 0, 0, 0);
        a1 = __builtin_amdgcn_mfma_f32_32x32x16_bf16(afr[s], bA[4 + s], a1, 0, 0, 0);
        a2 = __builtin_amdgcn_mfma_f32_32x32x16_bf16(afr[4 + s], bA[s], a2, 0, 0, 0);
      }
      int ci = 2 * i * 32 + m;
      #pragma unroll
      for (int j = 0; j < 16; j++) {
        float sc = fmaf(-2.f, a0[j] + a1[j] + a2[j], enA);
        if (sc < bsc[j]) { bsc[j] = sc; bix[j] = ci; }  // ascending ci: ties -> smaller
      }
    }
    if (i < 15) {
      const unsigned short* p = eb + (2 * i + 2) * 4096;
      #pragma unroll
      for (int s = 0; s < 4; s++) {
        bA[s]     = *(const short8*)(p + s * 512);
        bA[4 + s] = *(const short8*)(p + 2048 + s * 512);
      }
      enA = enorm[(2 * i + 2) * 32 + m];
    }
    {
      float16v a0 = {}, a1 = {}, a2 = {};
      #pragma unroll
      for (int s = 0; s < 4; s++) {
        a0 = __builtin_amdgcn_mfma_f32_32x32x16_bf16(afr[s], bB[s], a0, 0, 0, 0);
        a1 = __builtin_amdgcn_mfma_f32_32x32x16_bf16(afr[s], bB[4 + s], a1, 0, 0, 0);
        a2 = __builtin_amdgcn_mfma_f32_32x32x16_bf16(afr[4 + s], bB[s], a2, 0, 0, 0);
      }
      int ci = tB * 32 + m;
      #pragma unroll
      for (int j = 0; j < 16; j++) {
        float sc = fmaf(-2.f, a0[j] + a1[j] + a2[j], enB);
        if (sc < bsc[j]) { bsc[j] = sc; bix[j] = ci; }
      }
    }
  }

  // C layout: row = (j&3)+8*(j>>2)+4*half, col = m. Butterfly min over cols.
  #pragma unroll
  for (int j = 0; j < 16; j++) {
    unsigned long long key =
        ((unsigned long long)orderf(bsc[j]) << 32) | (unsigned int)bix[j];
    #pragma unroll
    for (int mm = 1; mm < 32; mm <<= 1) {
      unsigned long long o = shfl_xor_u64(key, mm);
      if (o < key) key = o;
    }
    if (m == 0) {
      int row_local = (j & 3) + 8 * (j >> 2) + 4 * half;
      int grow = row_base + row_local;
      int cidx = (int)(key & 0xffffffffull);
      idx_ws[grow] = cidx;
      outidx[grow] = (float)cidx;
    }
  }
}

// ---------------------------------------------------------------------------
// out + KL: 1024 blocks; block = 64 rows x 4 d-chunks of 16 (chunk = wave).
// __expf/__logf (single v_exp/v_log) instead of ocml expf/logf — the exp
// evaluation (4.2M calls) was the hidden VALU cost of this kernel.
// ---------------------------------------------------------------------------
__launch_bounds__(256)
__global__ void out_kl_kernel(const float* __restrict__ inp,
                              const float* __restrict__ Ew,
                              const float* __restrict__ SE,
                              const int* __restrict__ idx_ws,
                              float* __restrict__ out,
                              float* __restrict__ klacc) {
  __shared__ float Zs[4][64], S1s[4][64], Us[4][64];
  const int tid = threadIdx.x;
  const int c = tid >> 6;       // d-chunk (= wave)
  const int i = tid & 63;       // row within block
  const int r = blockIdx.x * 64 + i;
  const int b = r >> 12, l = r & 4095;
  const float* xp = inp + (size_t)b * DDIM * LDIM + l;
  float* op = out + (size_t)b * DDIM * LDIM + l;
  const int k = idx_ws[r];
  const float4* Ek4 = (const float4*)(Ew + k * DDIM) + c * 4;
  const float4* Qk4 = (const float4*)(SE + k * DDIM) + c * 4;

  float Z = 0.f, S1 = 0.f, U = 0.f;
  #pragma unroll
  for (int t = 0; t < 4; t++) {
    float ek[4], qk[4];
    *(float4*)ek = Ek4[t];
    *(float4*)qk = Qk4[t];
    #pragma unroll
    for (int u = 0; u < 4; u++) {
      int d = c * 16 + t * 4 + u;
      float x = xp[(size_t)d * LDIM];
      float e = __expf(x);
      Z += e;
      S1 += e * x;
      U += e * qk[u];
      op[(size_t)d * LDIM] = ek[u];
    }
  }
  Zs[c][i] = Z; S1s[c][i] = S1; Us[c][i] = U;
  __syncthreads();
  if (tid < 64) {
    float Zt = Zs[0][i] + Zs[1][i] + Zs[2][i] + Zs[3][i];
    float S1t = S1s[0][i] + S1s[1][i] + S1s[2][i] + S1s[3][i];
    float Ut = Us[0][i] + Us[1][i] + Us[2][i] + Us[3][i];
    float kl = (S1t - Ut) / Zt - __logf(Zt);
    #pragma unroll
    for (int o = 32; o > 0; o >>= 1) kl += __shfl_xor(kl, o, 64);
    if (i == 0) atomicAdd(klacc, kl);
  }
}

// ---------------------------------------------------------------------------
// dw partial: dimension-sliced histogram, 512 thr/block; d==0 blocks also
// histogram counts. Zero global atomics.
// ---------------------------------------------------------------------------
__launch_bounds__(512)
__global__ void dw_partial_kernel(const float* __restrict__ inp,
                                  const int* __restrict__ idx_ws,
                                  float* __restrict__ partial,
                                  float* __restrict__ pcounts) {
  __shared__ float dwp[KCODES];
  __shared__ float cnt[KCODES];
  const int d = blockIdx.x & 63;
  const int slice = blockIdx.x >> 6;
  const int tid = threadIdx.x;
  const bool do_cnt = (d == 0);

  #pragma unroll
  for (int i = 0; i < KCODES / 512; i++) {
    dwp[tid + i * 512] = 0.f;
    cnt[tid + i * 512] = 0.f;
  }
  __syncthreads();

  const int r0 = slice * SLICE_ROWS;
  for (int i = tid; i < SLICE_ROWS; i += 512) {
    int r = r0 + i;
    int b = r >> 12, l = r & 4095;
    float x = inp[(size_t)b * DDIM * LDIM + (size_t)d * LDIM + l];
    int k = idx_ws[r];
    atomicAdd(&dwp[k], x);
    if (do_cnt) atomicAdd(&cnt[k], 1.0f);
  }
  __syncthreads();

  float* dst = partial + ((size_t)slice * 64 + d) * KCODES;
  #pragma unroll
  for (int i = 0; i < KCODES / 512; i++) dst[tid + i * 512] = dwp[tid + i * 512];
  if (do_cnt) {
    float* cd = pcounts + (size_t)slice * KCODES;
    #pragma unroll
    for (int i = 0; i < KCODES / 512; i++) cd[tid + i * 512] = cnt[tid + i * 512];
  }
}

// ---------------------------------------------------------------------------
// csp + perplexity (from count partials). 1 block x 1024.
// ---------------------------------------------------------------------------
__global__ void csp_kernel(const float* __restrict__ ema_cs,
                           const float* __restrict__ pcounts,
                           float* __restrict__ csp,
                           float* __restrict__ perp_out) {
  __shared__ float red1[16], red2[16];
  int k = threadIdx.x;
  float c = 0.f;
  #pragma unroll
  for (int sl = 0; sl < NSLICE; sl++) c += pcounts[sl * KCODES + k];
  float cs = ema_cs[k] * 0.9f + 0.1f * c;
  float n = cs;
  #pragma unroll
  for (int o = 32; o > 0; o >>= 1) n += __shfl_xor(n, o, 64);
  if ((k & 63) == 0) red1[k >> 6] = n;
  float a = c * (1.0f / 65536.0f);
  float ent = a * logf(a + 1e-10f);
  float es = ent;
  #pragma unroll
  for (int o = 32; o > 0; o >>= 1) es += __shfl_xor(es, o, 64);
  if ((k & 63) == 0) red2[k >> 6] = es;
  __syncthreads();
  if (k == 0) {
    float t1 = 0.f, t2 = 0.f;
    for (int i = 0; i < 16; i++) { t1 += red1[i]; t2 += red2[i]; }
    red1[0] = t1;
    *perp_out = expf(-t2);
  }
  __syncthreads();
  float N = red1[0];
  csp[k] = (cs + 1e-5f) / (N + 1024.0f * 1e-5f) * N;
}

// ---------------------------------------------------------------------------
// reduce partials + embed epilogue + loss scalar.
// ---------------------------------------------------------------------------
__launch_bounds__(256)
__global__ void reduce_embed_kernel(const float* __restrict__ partial,
                                    const float* __restrict__ emaw,
                                    const float* __restrict__ csp,
                                    const float* __restrict__ klacc,
                                    float* __restrict__ emb_out,
                                    float* __restrict__ loss_out) {
  int i = blockIdx.x * 256 + threadIdx.x;
  int k = i >> 6, d = i & 63;
  float s = 0.f;
  #pragma unroll
  for (int sl = 0; sl < NSLICE; sl++)
    s += partial[((size_t)sl * 64 + d) * KCODES + k];
  float v = fmaf(0.1f, s, emaw[i] * 0.9f);
  emb_out[i] = v / csp[k];
  if (i == 0) *loss_out = 0.1f * (*klacc) * (1.0f / 16.0f);
}

extern "C" void kernel_launch(void* const* d_in, const int* in_sizes, int n_in,
                              void* d_out, int out_size, void* d_ws, size_t ws_size,
                              hipStream_t stream) {
  const float* inp   = (const float*)d_in[0];   // (16,64,4096)
  const float* Ew    = (const float*)d_in[1];   // (1024,64)
  const float* emacs = (const float*)d_in[2];   // (1024,)
  const float* emaw  = (const float*)d_in[3];   // (1024,64)

  float* out      = (float*)d_out;              // (16,64,4096) = 4194304
  float* loss_out = out + 4194304;
  float* perp_out = out + 4194305;
  float* emb_out  = out + 4194306;              // 65536
  float* idxf_out = out + 4194306 + 65536;      // 65536 (indices as float)

  char* ws = (char*)d_ws;
  int*   idx_ws  = (int*)(ws);                  // 262144 B
  float* klacc   = (float*)(ws + 262144);       // 256 B (zeroed)
  float* enorm   = (float*)(ws + 266496);       // 4096 B
  float* csp     = (float*)(ws + 270592);       // 4096 B
  float* SE      = (float*)(ws + 274688);       // 262144 B -> ends 536832
  unsigned short* Epk2 = (unsigned short*)(ws + 536832);  // 262144 B
  // dw partials alias Epk2 (dead after argmin)
  float* partial = (float*)(ws + 536832);       // 2097152 B -> ends 2633984
  float* pcounts = (float*)(ws + 2633984);      // 32768 B  -> ends 2666752

  hipMemsetAsync(ws + 262144, 0, 256, stream);

  prep_kernel<<<KCODES, 64, 0, stream>>>(Ew, enorm, SE, Epk2);
  argmin_kernel<<<512, 256, 0, stream>>>(inp, Epk2, enorm, idx_ws, idxf_out);
  dw_partial_kernel<<<64 * NSLICE, 512, 0, stream>>>(inp, idx_ws, partial, pcounts);
  csp_kernel<<<1, 1024, 0, stream>>>(emacs, pcounts, csp, perp_out);
  out_kl_kernel<<<NROWS / 64, 256, 0, stream>>>(inp, Ew, SE, idx_ws, out, klacc);
  reduce_embed_kernel<<<NROWS / 256, 256, 0, stream>>>(partial, emaw, csp, klacc,
                                                       emb_out, loss_out);
}

// Round 12
// 164.084 us; speedup vs baseline: 1.2054x; 1.0898x over previous
//
#include <hip/hip_runtime.h>

#define LDIM 4096
#define DDIM 64
#define KCODES 1024
#define BDIM 16
#define NROWS 65536   // BDIM * LDIM
#define NSLICE 8
#define SLICE_ROWS (NROWS / NSLICE)   // 8192

typedef __attribute__((ext_vector_type(8))) short short8;
typedef __attribute__((ext_vector_type(16))) float float16v;

__device__ __forceinline__ unsigned int orderf(float f) {
  unsigned int u = __float_as_uint(f);
  return (u & 0x80000000u) ? ~u : (u | 0x80000000u);
}

__device__ __forceinline__ unsigned long long shfl_xor_u64(unsigned long long v, int m) {
  int lo = __shfl_xor((int)(unsigned int)(v & 0xffffffffull), m, 64);
  int hi = __shfl_xor((int)(unsigned int)(v >> 32), m, 64);
  return ((unsigned long long)(unsigned int)hi << 32) | (unsigned int)lo;
}

// bf16 RNE high part (as ushort bits)
__device__ __forceinline__ unsigned int bf16_rne(float x) {
  unsigned int u = __float_as_uint(x);
  return (u + 0x7FFFu + ((u >> 16) & 1u)) >> 16;
}

// ---------------------------------------------------------------------------
// prep: per-code norm + softmax table + FRAGMENT-LOAD-ORDER bf16 codebook.
// For tile t (32 codes), frag q (0..3 hi s, 4..7 lo s), lane (h*32+m):
// 8 shorts = B-frag of code c=t*32+m, dims d=16s+8h+[0,8). Short index:
// t*4096 + q*512 + (h*32+m)*8 + j -> contiguous 1 KB per wave load.
// ---------------------------------------------------------------------------
__global__ void prep_kernel(const float* __restrict__ Ew,
                            float* __restrict__ enorm,
                            float* __restrict__ SE,
                            unsigned short* __restrict__ Epk2) {
  int k = blockIdx.x;
  int d = threadIdx.x;
  float v = Ew[k * DDIM + d];
  float n2 = v * v;
  #pragma unroll
  for (int o = 32; o > 0; o >>= 1) n2 += __shfl_xor(n2, o, 64);
  float m = v;
  #pragma unroll
  for (int o = 32; o > 0; o >>= 1) m = fmaxf(m, __shfl_xor(m, o, 64));
  float e = __expf(v - m);
  float Z = e;
  #pragma unroll
  for (int o = 32; o > 0; o >>= 1) Z += __shfl_xor(Z, o, 64);
  SE[k * DDIM + d] = e / Z;
  if (d == 0) enorm[k] = n2;

  unsigned int rh = bf16_rne(v);
  float hif = __uint_as_float(rh << 16);
  unsigned int rl = bf16_rne(v - hif);
  int tile = k >> 5, mm = k & 31;
  int s = d >> 4, h = (d >> 3) & 1, j = d & 7;
  int base = tile * 4096 + (h * 32 + mm) * 8 + j;
  Epk2[base + s * 512]        = (unsigned short)rh;
  Epk2[base + (4 + s) * 512]  = (unsigned short)rl;
}

// ---------------------------------------------------------------------------
// argmin (R8 structure — best measured): LDS-free, barrier-free, atomic-free.
// One wave owns 32 rows; B streamed from the fragment-linear codebook
// (contiguous 1 KB wave loads, sequential, L1/L2-hot); register dbuf;
// 3 independent MFMA chains; butterfly argmin; direct writes.
// score = ||E||^2 - 2 x.E  (row-constant ||x||^2 dropped; order/ties kept).
// ---------------------------------------------------------------------------
__launch_bounds__(256, 2)
__global__ void argmin_kernel(const float* __restrict__ inp,
                              const unsigned short* __restrict__ Epk2,
                              const float* __restrict__ enorm,
                              int* __restrict__ idx_ws,
                              float* __restrict__ outidx) {
  const int tid = threadIdx.x;
  const int lane = tid & 63;
  const int w = tid >> 6;
  const int half = lane >> 5;
  const int m = lane & 31;
  const int row_base = blockIdx.x * 128 + w * 32;
  const int b = row_base >> 12;
  const int l0 = row_base & 4095;
  const float* xp = inp + (size_t)b * DDIM * LDIM + l0 + m;

  short8 afr[8];   // 0..3 = hi frags, 4..7 = lo frags
  #pragma unroll
  for (int s = 0; s < 4; s++) {
    #pragma unroll
    for (int j = 0; j < 8; j++) {
      int d = 16 * s + 8 * half + j;
      float x = xp[(size_t)d * LDIM];
      unsigned int rh = bf16_rne(x);
      float hif = __uint_as_float(rh << 16);
      unsigned int rl = bf16_rne(x - hif);
      afr[s][j] = (short)(unsigned short)rh;
      afr[4 + s][j] = (short)(unsigned short)rl;
    }
  }

  float bsc[16];
  int bix[16];
  #pragma unroll
  for (int j = 0; j < 16; j++) { bsc[j] = 1e30f; bix[j] = 0; }

  const unsigned short* eb = Epk2 + lane * 8;

  short8 bA[8], bB[8];
  float enA, enB;

  #pragma unroll
  for (int s = 0; s < 4; s++) {
    bA[s]     = *(const short8*)(eb + s * 512);
    bA[4 + s] = *(const short8*)(eb + 2048 + s * 512);
  }
  enA = enorm[m];

  #pragma unroll 1
  for (int i = 0; i < 16; i++) {
    const int tB = 2 * i + 1;
    {
      const unsigned short* p = eb + tB * 4096;
      #pragma unroll
      for (int s = 0; s < 4; s++) {
        bB[s]     = *(const short8*)(p + s * 512);
        bB[4 + s] = *(const short8*)(p + 2048 + s * 512);
      }
      enB = enorm[tB * 32 + m];
    }
    {
      float16v a0 = {}, a1 = {}, a2 = {};
      #pragma unroll
      for (int s = 0; s < 4; s++) {
        a0 = __builtin_amdgcn_mfma_f32_32x32x16_bf16(afr[s], bA[s], a0, 0, 0, 0);
        a1 = __builtin_amdgcn_mfma_f32_32x32x16_bf16(afr[s], bA[4 + s], a1, 0, 0, 0);
        a2 = __builtin_amdgcn_mfma_f32_32x32x16_bf16(afr[4 + s], bA[s], a2, 0, 0, 0);
      }
      int ci = 2 * i * 32 + m;
      #pragma unroll
      for (int j = 0; j < 16; j++) {
        float sc = fmaf(-2.f, a0[j] + a1[j] + a2[j], enA);
        if (sc < bsc[j]) { bsc[j] = sc; bix[j] = ci; }  // ascending ci: ties -> smaller
      }
    }
    if (i < 15) {
      const unsigned short* p = eb + (2 * i + 2) * 4096;
      #pragma unroll
      for (int s = 0; s < 4; s++) {
        bA[s]     = *(const short8*)(p + s * 512);
        bA[4 + s] = *(const short8*)(p + 2048 + s * 512);
      }
      enA = enorm[(2 * i + 2) * 32 + m];
    }
    {
      float16v a0 = {}, a1 = {}, a2 = {};
      #pragma unroll
      for (int s = 0; s < 4; s++) {
        a0 = __builtin_amdgcn_mfma_f32_32x32x16_bf16(afr[s], bB[s], a0, 0, 0, 0);
        a1 = __builtin_amdgcn_mfma_f32_32x32x16_bf16(afr[s], bB[4 + s], a1, 0, 0, 0);
        a2 = __builtin_amdgcn_mfma_f32_32x32x16_bf16(afr[4 + s], bB[s], a2, 0, 0, 0);
      }
      int ci = tB * 32 + m;
      #pragma unroll
      for (int j = 0; j < 16; j++) {
        float sc = fmaf(-2.f, a0[j] + a1[j] + a2[j], enB);
        if (sc < bsc[j]) { bsc[j] = sc; bix[j] = ci; }
      }
    }
  }

  #pragma unroll
  for (int j = 0; j < 16; j++) {
    unsigned long long key =
        ((unsigned long long)orderf(bsc[j]) << 32) | (unsigned int)bix[j];
    #pragma unroll
    for (int mm = 1; mm < 32; mm <<= 1) {
      unsigned long long o = shfl_xor_u64(key, mm);
      if (o < key) key = o;
    }
    if (m == 0) {
      int row_local = (j & 3) + 8 * (j >> 2) + 4 * half;
      int grow = row_base + row_local;
      int cidx = (int)(key & 0xffffffffull);
      idx_ws[grow] = cidx;
      outidx[grow] = (float)cidx;
    }
  }
}

// ---------------------------------------------------------------------------
// MERGED out+KL / dw-partial dispatch (independent workloads, one launch):
// blocks [0,1024): out+KL — 64 rows x 4 d-chunks, coalesced, LDS combine,
//   one kl atomic per block.
// blocks [1024,1536): dw — dimension-sliced LDS histogram (d = bid&63,
//   slice = bid>>6); d==0 blocks also histogram counts. Zero global atomics.
// ---------------------------------------------------------------------------
__launch_bounds__(256)
__global__ void outkl_dw_kernel(const float* __restrict__ inp,
                                const float* __restrict__ Ew,
                                const float* __restrict__ SE,
                                const int* __restrict__ idx_ws,
                                float* __restrict__ out,
                                float* __restrict__ klacc,
                                float* __restrict__ partial,
                                float* __restrict__ pcounts) {
  __shared__ float lds[2 * KCODES];   // dw: dwp+cnt; out: Z/S1/U (3*256)
  const int tid = threadIdx.x;

  if (blockIdx.x < 1024) {
    float* Zs  = lds;            // [4][64]
    float* S1s = lds + 256;      // [4][64]
    float* Us  = lds + 512;      // [4][64]
    const int c = tid >> 6;
    const int i = tid & 63;
    const int r = blockIdx.x * 64 + i;
    const int b = r >> 12, l = r & 4095;
    const float* xp = inp + (size_t)b * DDIM * LDIM + l;
    float* op = out + (size_t)b * DDIM * LDIM + l;
    const int k = idx_ws[r];
    const float4* Ek4 = (const float4*)(Ew + k * DDIM) + c * 4;
    const float4* Qk4 = (const float4*)(SE + k * DDIM) + c * 4;

    float Z = 0.f, S1 = 0.f, U = 0.f;
    #pragma unroll
    for (int t = 0; t < 4; t++) {
      float ek[4], qk[4];
      *(float4*)ek = Ek4[t];
      *(float4*)qk = Qk4[t];
      #pragma unroll
      for (int u = 0; u < 4; u++) {
        int d = c * 16 + t * 4 + u;
        float x = xp[(size_t)d * LDIM];
        float e = __expf(x);
        Z += e;
        S1 += e * x;
        U += e * qk[u];
        op[(size_t)d * LDIM] = ek[u];
      }
    }
    Zs[c * 64 + i] = Z; S1s[c * 64 + i] = S1; Us[c * 64 + i] = U;
    __syncthreads();
    if (tid < 64) {
      float Zt = Zs[i] + Zs[64 + i] + Zs[128 + i] + Zs[192 + i];
      float S1t = S1s[i] + S1s[64 + i] + S1s[128 + i] + S1s[192 + i];
      float Ut = Us[i] + Us[64 + i] + Us[128 + i] + Us[192 + i];
      float kl = (S1t - Ut) / Zt - __logf(Zt);
      #pragma unroll
      for (int o = 32; o > 0; o >>= 1) kl += __shfl_xor(kl, o, 64);
      if (i == 0) atomicAdd(klacc, kl);
    }
  } else {
    float* dwp = lds;            // [1024]
    float* cnt = lds + KCODES;   // [1024]
    const int bid = blockIdx.x - 1024;
    const int d = bid & 63;
    const int slice = bid >> 6;
    const bool do_cnt = (d == 0);

    #pragma unroll
    for (int i = 0; i < KCODES / 256; i++) {
      dwp[tid + i * 256] = 0.f;
      cnt[tid + i * 256] = 0.f;
    }
    __syncthreads();

    const int r0 = slice * SLICE_ROWS;
    for (int i = tid; i < SLICE_ROWS; i += 256) {
      int r = r0 + i;
      int b = r >> 12, l = r & 4095;
      float x = inp[(size_t)b * DDIM * LDIM + (size_t)d * LDIM + l];
      int k = idx_ws[r];
      atomicAdd(&dwp[k], x);
      if (do_cnt) atomicAdd(&cnt[k], 1.0f);
    }
    __syncthreads();

    float* dst = partial + ((size_t)slice * 64 + d) * KCODES;
    #pragma unroll
    for (int i = 0; i < KCODES / 256; i++) dst[tid + i * 256] = dwp[tid + i * 256];
    if (do_cnt) {
      float* cd = pcounts + (size_t)slice * KCODES;
      #pragma unroll
      for (int i = 0; i < KCODES / 256; i++) cd[tid + i * 256] = cnt[tid + i * 256];
    }
  }
}

// ---------------------------------------------------------------------------
// finalize: dw reduce + csp inline (N = 0.9*sum(ema_cs) + 0.1*NROWS, known
// without the counts reduction) + embed epilogue; block 0 also computes
// perplexity (from pcounts) and the loss scalar.
// ---------------------------------------------------------------------------
__launch_bounds__(256)
__global__ void finalize_kernel(const float* __restrict__ partial,
                                const float* __restrict__ pcounts,
                                const float* __restrict__ emaw,
                                const float* __restrict__ emacs,
                                const float* __restrict__ klacc,
                                float* __restrict__ emb_out,
                                float* __restrict__ loss_out,
                                float* __restrict__ perp_out) {
  __shared__ float red[4], red2[4];
  const int tid = threadIdx.x;
  const int i = blockIdx.x * 256 + tid;
  const int k = i >> 6, d = i & 63;

  // redundant per-block reduction of sum(ema_cs) (4 KB, L2-hot)
  float se = 0.f;
  #pragma unroll
  for (int t = 0; t < 4; t++) se += emacs[tid * 4 + t];
  #pragma unroll
  for (int o = 32; o > 0; o >>= 1) se += __shfl_xor(se, o, 64);
  if ((tid & 63) == 0) red[tid >> 6] = se;
  __syncthreads();
  const float S = red[0] + red[1] + red[2] + red[3];
  const float N = 0.9f * S + 0.1f * (float)NROWS;

  float c = 0.f;
  #pragma unroll
  for (int sl = 0; sl < NSLICE; sl++) c += pcounts[sl * KCODES + k];
  float cs = fmaf(0.1f, c, emacs[k] * 0.9f);
  float csp = (cs + 1e-5f) / (N + (float)KCODES * 1e-5f) * N;

  float s = 0.f;
  #pragma unroll
  for (int sl = 0; sl < NSLICE; sl++)
    s += partial[((size_t)sl * 64 + d) * KCODES + k];
  emb_out[i] = fmaf(0.1f, s, emaw[i] * 0.9f) / csp;

  if (blockIdx.x == 0) {
    float es = 0.f;
    #pragma unroll
    for (int t = 0; t < 4; t++) {
      int kk = tid * 4 + t;
      float cc = 0.f;
      #pragma unroll
      for (int sl = 0; sl < NSLICE; sl++) cc += pcounts[sl * KCODES + kk];
      float a = cc * (1.0f / (float)NROWS);
      es += a * logf(a + 1e-10f);
    }
    #pragma unroll
    for (int o = 32; o > 0; o >>= 1) es += __shfl_xor(es, o, 64);
    if ((tid & 63) == 0) red2[tid >> 6] = es;
    __syncthreads();
    if (tid == 0) {
      *perp_out = expf(-(red2[0] + red2[1] + red2[2] + red2[3]));
      *loss_out = 0.1f * (*klacc) * (1.0f / 16.0f);
    }
  }
}

extern "C" void kernel_launch(void* const* d_in, const int* in_sizes, int n_in,
                              void* d_out, int out_size, void* d_ws, size_t ws_size,
                              hipStream_t stream) {
  const float* inp   = (const float*)d_in[0];   // (16,64,4096)
  const float* Ew    = (const float*)d_in[1];   // (1024,64)
  const float* emacs = (const float*)d_in[2];   // (1024,)
  const float* emaw  = (const float*)d_in[3];   // (1024,64)

  float* out      = (float*)d_out;              // (16,64,4096) = 4194304
  float* loss_out = out + 4194304;
  float* perp_out = out + 4194305;
  float* emb_out  = out + 4194306;              // 65536
  float* idxf_out = out + 4194306 + 65536;      // 65536 (indices as float)

  char* ws = (char*)d_ws;
  int*   idx_ws  = (int*)(ws);                  // 262144 B
  float* klacc   = (float*)(ws + 262144);       // 256 B (zeroed)
  float* enorm   = (float*)(ws + 266496);       // 4096 B
  float* SE      = (float*)(ws + 274688);       // 262144 B -> ends 536832
  unsigned short* Epk2 = (unsigned short*)(ws + 536832);  // 262144 B
  // dw partials alias Epk2 (dead after argmin)
  float* partial = (float*)(ws + 536832);       // 2097152 B -> ends 2633984
  float* pcounts = (float*)(ws + 2633984);      // 32768 B  -> ends 2666752

  hipMemsetAsync(ws + 262144, 0, 256, stream);

  prep_kernel<<<KCODES, 64, 0, stream>>>(Ew, enorm, SE, Epk2);
  argmin_kernel<<<512, 256, 0, stream>>>(inp, Epk2, enorm, idx_ws, idxf_out);
  outkl_dw_kernel<<<1536, 256, 0, stream>>>(inp, Ew, SE, idx_ws, out, klacc,
                                            partial, pcounts);
  finalize_kernel<<<NROWS / 256, 256, 0, stream>>>(partial, pcounts, emaw, emacs,
                                                   klacc, emb_out, loss_out,
                                                   perp_out);
}

// Round 13
// 162.700 us; speedup vs baseline: 1.2157x; 1.0085x over previous
//
#include <hip/hip_runtime.h>

#define LDIM 4096
#define DDIM 64
#define KCODES 1024
#define BDIM 16
#define NROWS 65536   // BDIM * LDIM
#define NSLICE 8
#define SLICE_ROWS (NROWS / NSLICE)   // 8192

typedef __attribute__((ext_vector_type(8))) short short8;
typedef __attribute__((ext_vector_type(16))) float float16v;

__device__ __forceinline__ unsigned int orderf(float f) {
  unsigned int u = __float_as_uint(f);
  return (u & 0x80000000u) ? ~u : (u | 0x80000000u);
}

__device__ __forceinline__ unsigned long long shfl_xor_u64(unsigned long long v, int m) {
  int lo = __shfl_xor((int)(unsigned int)(v & 0xffffffffull), m, 64);
  int hi = __shfl_xor((int)(unsigned int)(v >> 32), m, 64);
  return ((unsigned long long)(unsigned int)hi << 32) | (unsigned int)lo;
}

// bf16 RNE high part (as ushort bits)
__device__ __forceinline__ unsigned int bf16_rne(float x) {
  unsigned int u = __float_as_uint(x);
  return (u + 0x7FFFu + ((u >> 16) & 1u)) >> 16;
}

// ---------------------------------------------------------------------------
// prep: per-code norm + softmax table + FRAGMENT-LOAD-ORDER bf16 codebook.
// ---------------------------------------------------------------------------
__global__ void prep_kernel(const float* __restrict__ Ew,
                            float* __restrict__ enorm,
                            float* __restrict__ SE,
                            unsigned short* __restrict__ Epk2) {
  int k = blockIdx.x;
  int d = threadIdx.x;
  float v = Ew[k * DDIM + d];
  float n2 = v * v;
  #pragma unroll
  for (int o = 32; o > 0; o >>= 1) n2 += __shfl_xor(n2, o, 64);
  float m = v;
  #pragma unroll
  for (int o = 32; o > 0; o >>= 1) m = fmaxf(m, __shfl_xor(m, o, 64));
  float e = __expf(v - m);
  float Z = e;
  #pragma unroll
  for (int o = 32; o > 0; o >>= 1) Z += __shfl_xor(Z, o, 64);
  SE[k * DDIM + d] = e / Z;
  if (d == 0) enorm[k] = n2;

  unsigned int rh = bf16_rne(v);
  float hif = __uint_as_float(rh << 16);
  unsigned int rl = bf16_rne(v - hif);
  int tile = k >> 5, mm = k & 31;
  int s = d >> 4, h = (d >> 3) & 1, j = d & 7;
  int base = tile * 4096 + (h * 32 + mm) * 8 + j;
  Epk2[base + s * 512]        = (unsigned short)rh;
  Epk2[base + (4 + s) * 512]  = (unsigned short)rl;
}

// ---------------------------------------------------------------------------
// argmin (R8 structure — best measured): LDS-free, barrier-free, atomic-free.
// ---------------------------------------------------------------------------
__launch_bounds__(256, 2)
__global__ void argmin_kernel(const float* __restrict__ inp,
                              const unsigned short* __restrict__ Epk2,
                              const float* __restrict__ enorm,
                              int* __restrict__ idx_ws,
                              float* __restrict__ outidx) {
  const int tid = threadIdx.x;
  const int lane = tid & 63;
  const int w = tid >> 6;
  const int half = lane >> 5;
  const int m = lane & 31;
  const int row_base = blockIdx.x * 128 + w * 32;
  const int b = row_base >> 12;
  const int l0 = row_base & 4095;
  const float* xp = inp + (size_t)b * DDIM * LDIM + l0 + m;

  short8 afr[8];
  #pragma unroll
  for (int s = 0; s < 4; s++) {
    #pragma unroll
    for (int j = 0; j < 8; j++) {
      int d = 16 * s + 8 * half + j;
      float x = xp[(size_t)d * LDIM];
      unsigned int rh = bf16_rne(x);
      float hif = __uint_as_float(rh << 16);
      unsigned int rl = bf16_rne(x - hif);
      afr[s][j] = (short)(unsigned short)rh;
      afr[4 + s][j] = (short)(unsigned short)rl;
    }
  }

  float bsc[16];
  int bix[16];
  #pragma unroll
  for (int j = 0; j < 16; j++) { bsc[j] = 1e30f; bix[j] = 0; }

  const unsigned short* eb = Epk2 + lane * 8;

  short8 bA[8], bB[8];
  float enA, enB;

  #pragma unroll
  for (int s = 0; s < 4; s++) {
    bA[s]     = *(const short8*)(eb + s * 512);
    bA[4 + s] = *(const short8*)(eb + 2048 + s * 512);
  }
  enA = enorm[m];

  #pragma unroll 1
  for (int i = 0; i < 16; i++) {
    const int tB = 2 * i + 1;
    {
      const unsigned short* p = eb + tB * 4096;
      #pragma unroll
      for (int s = 0; s < 4; s++) {
        bB[s]     = *(const short8*)(p + s * 512);
        bB[4 + s] = *(const short8*)(p + 2048 + s * 512);
      }
      enB = enorm[tB * 32 + m];
    }
    {
      float16v a0 = {}, a1 = {}, a2 = {};
      #pragma unroll
      for (int s = 0; s < 4; s++) {
        a0 = __builtin_amdgcn_mfma_f32_32x32x16_bf16(afr[s], bA[s], a0, 0, 0, 0);
        a1 = __builtin_amdgcn_mfma_f32_32x32x16_bf16(afr[s], bA[4 + s], a1, 0, 0, 0);
        a2 = __builtin_amdgcn_mfma_f32_32x32x16_bf16(afr[4 + s], bA[s], a2, 0, 0, 0);
      }
      int ci = 2 * i * 32 + m;
      #pragma unroll
      for (int j = 0; j < 16; j++) {
        float sc = fmaf(-2.f, a0[j] + a1[j] + a2[j], enA);
        if (sc < bsc[j]) { bsc[j] = sc; bix[j] = ci; }  // ascending ci: ties -> smaller
      }
    }
    if (i < 15) {
      const unsigned short* p = eb + (2 * i + 2) * 4096;
      #pragma unroll
      for (int s = 0; s < 4; s++) {
        bA[s]     = *(const short8*)(p + s * 512);
        bA[4 + s] = *(const short8*)(p + 2048 + s * 512);
      }
      enA = enorm[(2 * i + 2) * 32 + m];
    }
    {
      float16v a0 = {}, a1 = {}, a2 = {};
      #pragma unroll
      for (int s = 0; s < 4; s++) {
        a0 = __builtin_amdgcn_mfma_f32_32x32x16_bf16(afr[s], bB[s], a0, 0, 0, 0);
        a1 = __builtin_amdgcn_mfma_f32_32x32x16_bf16(afr[s], bB[4 + s], a1, 0, 0, 0);
        a2 = __builtin_amdgcn_mfma_f32_32x32x16_bf16(afr[4 + s], bB[s], a2, 0, 0, 0);
      }
      int ci = tB * 32 + m;
      #pragma unroll
      for (int j = 0; j < 16; j++) {
        float sc = fmaf(-2.f, a0[j] + a1[j] + a2[j], enB);
        if (sc < bsc[j]) { bsc[j] = sc; bix[j] = ci; }
      }
    }
  }

  #pragma unroll
  for (int j = 0; j < 16; j++) {
    unsigned long long key =
        ((unsigned long long)orderf(bsc[j]) << 32) | (unsigned int)bix[j];
    #pragma unroll
    for (int mm = 1; mm < 32; mm <<= 1) {
      unsigned long long o = shfl_xor_u64(key, mm);
      if (o < key) key = o;
    }
    if (m == 0) {
      int row_local = (j & 3) + 8 * (j >> 2) + 4 * half;
      int grow = row_base + row_local;
      int cidx = (int)(key & 0xffffffffull);
      idx_ws[grow] = cidx;
      outidx[grow] = (float)cidx;
    }
  }
}

// ---------------------------------------------------------------------------
// MERGED dw / out+KL dispatch. dw blocks FIRST (no tail).
// blocks [0,512): dw — dimension-sliced LDS histogram (d=bid&63, slice=bid>>6)
// blocks [512,768): out+KL, 256 rows x 64 d per block, LDS-transposed:
//   per 16-d chunk: gather Ek/Qk row-segments into LDS (Et[d][row] plain;
//   Qt[d][g(row)] with g(row)=((row&3)<<6)|(row>>2) so compute reads are
//   conflict-free), then wave w handles 4 d-slices: x loaded float4 along l
//   (1 KB/instr), out stored float4 from Et via ds_read_b128 (1 KB/instr).
//   Per-row Z/S1/U partials reduced across waves in LDS; 1 KL atomic/block.
// ---------------------------------------------------------------------------
__launch_bounds__(256)
__global__ void outkl_dw_kernel(const float* __restrict__ inp,
                                const float* __restrict__ Ew,
                                const float* __restrict__ SE,
                                const int* __restrict__ idx_ws,
                                float* __restrict__ out,
                                float* __restrict__ klacc,
                                float* __restrict__ partial,
                                float* __restrict__ pcounts) {
  __shared__ float smem[11528];   // 46.1 KB (out branch); dw uses first 8 KB
  const int tid = threadIdx.x;

  if (blockIdx.x < 512) {
    // ---------------- dw: dimension-sliced histogram --------------------
    float* dwp = smem;            // [1024]
    float* cnt = smem + KCODES;   // [1024]
    const int d = blockIdx.x & 63;
    const int slice = blockIdx.x >> 6;
    const bool do_cnt = (d == 0);

    #pragma unroll
    for (int i = 0; i < KCODES / 256; i++) {
      dwp[tid + i * 256] = 0.f;
      cnt[tid + i * 256] = 0.f;
    }
    __syncthreads();

    const int r0 = slice * SLICE_ROWS;
    for (int i = tid; i < SLICE_ROWS; i += 256) {
      int r = r0 + i;
      int b = r >> 12, l = r & 4095;
      float x = inp[(size_t)b * DDIM * LDIM + (size_t)d * LDIM + l];
      int k = idx_ws[r];
      atomicAdd(&dwp[k], x);
      if (do_cnt) atomicAdd(&cnt[k], 1.0f);
    }
    __syncthreads();

    float* dst = partial + ((size_t)slice * 64 + d) * KCODES;
    #pragma unroll
    for (int i = 0; i < KCODES / 256; i++) dst[tid + i * 256] = dwp[tid + i * 256];
    if (do_cnt) {
      float* cd = pcounts + (size_t)slice * KCODES;
      #pragma unroll
      for (int i = 0; i < KCODES / 256; i++) cd[tid + i * 256] = cnt[tid + i * 256];
    }
  } else {
    // ---------------- out + KL: 256 rows, LDS transpose -----------------
    int*   kk  = (int*)smem;         // [256]
    float* Et  = smem + 256;         // [16][256]  (d-local x row)
    float* Qt  = smem + 4352;        // [16][256]  (d-local x g(row))
    float* Zp  = smem + 8448;        // [4][256]
    float* S1p = smem + 9472;        // [4][256]
    float* Up  = smem + 10496;       // [4][256]
    float* red4 = smem + 11520;      // [4]

    const int obid = blockIdx.x - 512;      // 0..255
    const int r0 = obid * 256;
    const int b = r0 >> 12;
    const int l0 = r0 & 4095;
    const float* xbase = inp + (size_t)b * DDIM * LDIM + l0;
    float* obase = out + (size_t)b * DDIM * LDIM + l0;
    const int w = tid >> 6, lane = tid & 63;

    kk[tid] = idx_ws[r0 + tid];
    __syncthreads();
    const int myk = kk[tid];
    const int gi = ((tid & 3) << 6) | (tid >> 2);   // swizzled row for Qt

    float Zc[4] = {0.f, 0.f, 0.f, 0.f};
    float S1c[4] = {0.f, 0.f, 0.f, 0.f};
    float Uc[4] = {0.f, 0.f, 0.f, 0.f};

    #pragma unroll 1
    for (int c = 0; c < 4; c++) {
      // gather: thread owns row tid; 16 floats of Ek & Qk (64 B sequential)
      {
        const float4* Ep = (const float4*)(Ew + myk * DDIM + c * 16);
        const float4* Qp = (const float4*)(SE + myk * DDIM + c * 16);
        #pragma unroll
        for (int q = 0; q < 4; q++) {
          float4 ev = Ep[q], qv = Qp[q];
          Et[(4 * q + 0) * 256 + tid] = ev.x;
          Et[(4 * q + 1) * 256 + tid] = ev.y;
          Et[(4 * q + 2) * 256 + tid] = ev.z;
          Et[(4 * q + 3) * 256 + tid] = ev.w;
          Qt[(4 * q + 0) * 256 + gi] = qv.x;
          Qt[(4 * q + 1) * 256 + gi] = qv.y;
          Qt[(4 * q + 2) * 256 + gi] = qv.z;
          Qt[(4 * q + 3) * 256 + gi] = qv.w;
        }
      }
      __syncthreads();
      // compute: wave w owns chunk-local d's dq = 4w..4w+3
      #pragma unroll
      for (int t = 0; t < 4; t++) {
        const int dq = 4 * w + t;
        const int d = c * 16 + dq;
        float4 xv = *(const float4*)(xbase + (size_t)d * LDIM + lane * 4);
        float4 ov = *(const float4*)&Et[dq * 256 + lane * 4];  // ds_read_b128
        *(float4*)(obase + (size_t)d * LDIM + lane * 4) = ov;  // 1 KB store
        #pragma unroll
        for (int j = 0; j < 4; j++) {
          float x = (j == 0) ? xv.x : (j == 1) ? xv.y : (j == 2) ? xv.z : xv.w;
          float e = __expf(x);
          Zc[j] += e;
          S1c[j] += e * x;
          Uc[j] += e * Qt[dq * 256 + (j << 6) + lane];   // conflict-free
        }
      }
      __syncthreads();   // before next chunk overwrites Et/Qt
    }

    // per-row reduce across waves: row = 4*lane + j
    #pragma unroll
    for (int j = 0; j < 4; j++) {
      Zp[w * 256 + 4 * lane + j] = Zc[j];
      S1p[w * 256 + 4 * lane + j] = S1c[j];
      Up[w * 256 + 4 * lane + j] = Uc[j];
    }
    __syncthreads();
    float Z = 0.f, S1 = 0.f, U = 0.f;
    #pragma unroll
    for (int w2 = 0; w2 < 4; w2++) {
      Z += Zp[w2 * 256 + tid];
      S1 += S1p[w2 * 256 + tid];
      U += Up[w2 * 256 + tid];
    }
    float kl = (S1 - U) / Z - __logf(Z);
    #pragma unroll
    for (int o = 32; o > 0; o >>= 1) kl += __shfl_xor(kl, o, 64);
    if (lane == 0) red4[w] = kl;
    __syncthreads();
    if (tid == 0)
      atomicAdd(klacc, red4[0] + red4[1] + red4[2] + red4[3]);
  }
}

// ---------------------------------------------------------------------------
// finalize: dw reduce + csp inline (N known algebraically) + embed epilogue;
// block 0 also computes perplexity and the loss scalar.
// ---------------------------------------------------------------------------
__launch_bounds__(256)
__global__ void finalize_kernel(const float* __restrict__ partial,
                                const float* __restrict__ pcounts,
                                const float* __restrict__ emaw,
                                const float* __restrict__ emacs,
                                const float* __restrict__ klacc,
                                float* __restrict__ emb_out,
                                float* __restrict__ loss_out,
                                float* __restrict__ perp_out) {
  __shared__ float red[4], red2[4];
  const int tid = threadIdx.x;
  const int i = blockIdx.x * 256 + tid;
  const int k = i >> 6, d = i & 63;

  float se = 0.f;
  #pragma unroll
  for (int t = 0; t < 4; t++) se += emacs[tid * 4 + t];
  #pragma unroll
  for (int o = 32; o > 0; o >>= 1) se += __shfl_xor(se, o, 64);
  if ((tid & 63) == 0) red[tid >> 6] = se;
  __syncthreads();
  const float S = red[0] + red[1] + red[2] + red[3];
  const float N = 0.9f * S + 0.1f * (float)NROWS;

  float c = 0.f;
  #pragma unroll
  for (int sl = 0; sl < NSLICE; sl++) c += pcounts[sl * KCODES + k];
  float cs = fmaf(0.1f, c, emacs[k] * 0.9f);
  float csp = (cs + 1e-5f) / (N + (float)KCODES * 1e-5f) * N;

  float s = 0.f;
  #pragma unroll
  for (int sl = 0; sl < NSLICE; sl++)
    s += partial[((size_t)sl * 64 + d) * KCODES + k];
  emb_out[i] = fmaf(0.1f, s, emaw[i] * 0.9f) / csp;

  if (blockIdx.x == 0) {
    float es = 0.f;
    #pragma unroll
    for (int t = 0; t < 4; t++) {
      int kk = tid * 4 + t;
      float cc = 0.f;
      #pragma unroll
      for (int sl = 0; sl < NSLICE; sl++) cc += pcounts[sl * KCODES + kk];
      float a = cc * (1.0f / (float)NROWS);
      es += a * logf(a + 1e-10f);
    }
    #pragma unroll
    for (int o = 32; o > 0; o >>= 1) es += __shfl_xor(es, o, 64);
    if ((tid & 63) == 0) red2[tid >> 6] = es;
    __syncthreads();
    if (tid == 0) {
      *perp_out = expf(-(red2[0] + red2[1] + red2[2] + red2[3]));
      *loss_out = 0.1f * (*klacc) * (1.0f / 16.0f);
    }
  }
}

extern "C" void kernel_launch(void* const* d_in, const int* in_sizes, int n_in,
                              void* d_out, int out_size, void* d_ws, size_t ws_size,
                              hipStream_t stream) {
  const float* inp   = (const float*)d_in[0];   // (16,64,4096)
  const float* Ew    = (const float*)d_in[1];   // (1024,64)
  const float* emacs = (const float*)d_in[2];   // (1024,)
  const float* emaw  = (const float*)d_in[3];   // (1024,64)

  float* out      = (float*)d_out;              // (16,64,4096) = 4194304
  float* loss_out = out + 4194304;
  float* perp_out = out + 4194305;
  float* emb_out  = out + 4194306;              // 65536
  float* idxf_out = out + 4194306 + 65536;      // 65536 (indices as float)

  char* ws = (char*)d_ws;
  int*   idx_ws  = (int*)(ws);                  // 262144 B
  float* klacc   = (float*)(ws + 262144);       // 256 B (zeroed)
  float* enorm   = (float*)(ws + 266496);       // 4096 B
  float* SE      = (float*)(ws + 274688);       // 262144 B -> ends 536832
  unsigned short* Epk2 = (unsigned short*)(ws + 536832);  // 262144 B
  // dw partials alias Epk2 (dead after argmin)
  float* partial = (float*)(ws + 536832);       // 2097152 B -> ends 2633984
  float* pcounts = (float*)(ws + 2633984);      // 32768 B  -> ends 2666752

  hipMemsetAsync(ws + 262144, 0, 256, stream);

  prep_kernel<<<KCODES, 64, 0, stream>>>(Ew, enorm, SE, Epk2);
  argmin_kernel<<<512, 256, 0, stream>>>(inp, Epk2, enorm, idx_ws, idxf_out);
  outkl_dw_kernel<<<768, 256, 0, stream>>>(inp, Ew, SE, idx_ws, out, klacc,
                                           partial, pcounts);
  finalize_kernel<<<NROWS / 256, 256, 0, stream>>>(partial, pcounts, emaw, emacs,
                                                   klacc, emb_out, loss_out,
                                                   perp_out);
}